// Round 8
// baseline (531.919 us; speedup 1.0000x reference)
//
#include <hip/hip_runtime.h>
#include <stdint.h>

// Problem constants (match reference)
#define S_TOK 16384
#define MDIM  1024
#define NEXP  64
#define CAP   256   // ceil(S/E * 1.0), >= MIN_CAPACITY

#define GBLK  512    // gate blocks (2 per CU)
#define GTOK  32     // tokens per gate block

static constexpr size_t SEC    = (size_t)S_TOK * NEXP * CAP;  // 268435456
static constexpr size_t CW_OFF = 1;                            // combine_weights
static constexpr size_t EC_OFF = 1 + 2 * SEC;                  // exp_counts (as float)
static constexpr size_t AL_OFF = EC_OFF + NEXP;                // alpha

// ---------------- Threefry-2x32-20 == jax.random.uniform(key(42), (S,E)) ----------------
__device__ __forceinline__ uint32_t rotl32(uint32_t x, int n) {
  return (x << n) | (x >> (32 - n));
}

__device__ float jax_u01(uint32_t i) {
  const uint32_t half = (uint32_t)(S_TOK * NEXP / 2);  // 524288
  uint32_t x0, x1;
  const bool hi = (i >= half);
  if (hi) { x0 = i - half; x1 = i; } else { x0 = i; x1 = i + half; }
  const uint32_t ks0 = 0u;
  const uint32_t ks1 = 42u;
  const uint32_t ks2 = 0x1BD11BDAu ^ ks0 ^ ks1;
  x0 += ks0; x1 += ks1;
#define TF_R(r) { x0 += x1; x1 = rotl32(x1, (r)); x1 ^= x0; }
  TF_R(13) TF_R(15) TF_R(26) TF_R(6)
  x0 += ks1; x1 += ks2 + 1u;
  TF_R(17) TF_R(29) TF_R(16) TF_R(24)
  x0 += ks2; x1 += ks0 + 2u;
  TF_R(13) TF_R(15) TF_R(26) TF_R(6)
  x0 += ks0; x1 += ks1 + 3u;
  TF_R(17) TF_R(29) TF_R(16) TF_R(24)
  x0 += ks1; x1 += ks2 + 4u;
  TF_R(13) TF_R(15) TF_R(26) TF_R(6)
  x0 += ks2; x1 += ks0 + 5u;
#undef TF_R
  const uint32_t bits = hi ? x1 : x0;
  return __uint_as_float((bits >> 9) | 0x3F800000u) - 1.0f;  // [0,1)
}

// ---------------- K1: gate GEMM (fp32) + softmax — 512 blocks, 2/CU ----------------
// 512 blocks x 256 threads, 32 tokens/block, acc[2][4] per thread.
__global__ __launch_bounds__(256) void k_gate(
    const float* __restrict__ x, const float* __restrict__ wg,
    float* __restrict__ out,
    int* __restrict__ expert_ws, float* __restrict__ uval_ws,
    float* __restrict__ alpha_ws, float* __restrict__ colsum_ws)
{
  __shared__ float xs[GTOK][68];  // x-tile; later reused for logits (swizzled cols)
  __shared__ float wsh[64][68];   // w-tile, XOR-swizzled float4 slots
  __shared__ float sm_m[GTOK], sm_inv[GTOK];

  const int tid  = threadIdx.x;
  const int tok0 = blockIdx.x * GTOK;
  const int tr   = tid >> 4;   // token group 0..15 (2 tokens each)
  const int tc   = tid & 15;   // expert group 0..15 (4 experts each)

  float acc[2][4] = {};
  float4 xr[2], wr[4];

  // prefetch chunk 0
#pragma unroll
  for (int i = 0; i < 2; ++i)
    xr[i] = *(const float4*)(x  + (size_t)(tok0 + tr + 16 * i) * MDIM + tc * 4);
#pragma unroll
  for (int i = 0; i < 4; ++i)
    wr[i] = *(const float4*)(wg + (size_t)(tr + 16 * i) * MDIM + tc * 4);

  for (int t = 0; t < 16; ++t) {
    __syncthreads();   // previous chunk's compute done
#pragma unroll
    for (int i = 0; i < 2; ++i)
      *(float4*)(&xs[tr + 16 * i][tc * 4]) = xr[i];
#pragma unroll
    for (int i = 0; i < 4; ++i) {
      const int r  = tr + 16 * i;
      const int fs = tc ^ ((r >> 2) & 7);
      *(float4*)(&wsh[r][fs * 4]) = wr[i];
    }
    if (t < 15) {      // issue next-chunk loads
      const int kc = (t + 1) * 64;
#pragma unroll
      for (int i = 0; i < 2; ++i)
        xr[i] = *(const float4*)(x  + (size_t)(tok0 + tr + 16 * i) * MDIM + kc + tc * 4);
#pragma unroll
      for (int i = 0; i < 4; ++i)
        wr[i] = *(const float4*)(wg + (size_t)(tr + 16 * i) * MDIM + kc + tc * 4);
    }
    __syncthreads();   // LDS tile visible
#pragma unroll
    for (int k4 = 0; k4 < 16; ++k4) {
      float4 a[2], b[4];
#pragma unroll
      for (int i = 0; i < 2; ++i)
        a[i] = *(const float4*)(&xs[tr * 2 + i][k4 * 4]);
#pragma unroll
      for (int j = 0; j < 4; ++j) {
        const int e  = tc * 4 + j;
        const int fs = k4 ^ ((e >> 2) & 7);
        b[j] = *(const float4*)(&wsh[e][fs * 4]);
      }
#pragma unroll
      for (int i = 0; i < 2; ++i)
#pragma unroll
        for (int j = 0; j < 4; ++j)
          acc[i][j] += a[i].x * b[j].x + a[i].y * b[j].y +
                       a[i].z * b[j].z + a[i].w * b[j].w;
    }
  }

  // Dump logits to LDS with +r column swizzle (bank-conflict-free softmax reads)
  __syncthreads();
#pragma unroll
  for (int i = 0; i < 2; ++i)
#pragma unroll
    for (int j = 0; j < 4; ++j) {
      const int r = tr * 2 + i, c = tc * 4 + j;
      xs[r][(c + r) & 63] = acc[i][j];
    }
  __syncthreads();

  // Pass 1: max/argmax + exp-sum per token (threads 0..GTOK-1)
  if (tid < GTOK) {
    const int t = tid;
    float mx = -3.0e38f; int am = 0;
    for (int e = 0; e < NEXP; ++e) {
      const float v = xs[t][(e + t) & 63];
      if (v > mx) { mx = v; am = e; }   // strict '>' == jnp.argmax first-max
    }
    float sum = 0.f;
    for (int e = 0; e < NEXP; ++e) sum += expf(xs[t][(e + t) & 63] - mx);
    const float inv = 1.0f / sum;        // gate at argmax == alpha
    sm_m[t] = mx; sm_inv[t] = inv;

    const int s = tok0 + t;
    expert_ws[s] = am;
    alpha_ws[s]  = inv;
    out[AL_OFF + s] = inv;
    uval_ws[s] = jax_u01((uint32_t)s * (uint32_t)NEXP + (uint32_t)am);
  }
  __syncthreads();

  // Pass 2: per-expert column sums of normalized gates (thread e = 0..63)
  if (tid < 64) {
    const int e = tid;
    float s = 0.f;
    for (int t = 0; t < GTOK; ++t)
      s += expf(xs[t][(e + t) & 63] - sm_m[t]) * sm_inv[t];
    colsum_ws[(size_t)blockIdx.x * 64 + e] = s;
  }
}

// ---------------- K2: per-expert capacity selection -> compact slotj table ----------------
__global__ __launch_bounds__(256) void k_select(
    const int* __restrict__ expert_ws, const float* __restrict__ uval_ws,
    int* __restrict__ slotj_ws, int* __restrict__ counts_ws,
    float* __restrict__ out)
{
  __shared__ float su[1024];
  __shared__ int   sidx[1024];
  __shared__ int   skept[1024];
  __shared__ int   scnt;

  const int e   = blockIdx.x;
  const int tid = threadIdx.x;
  if (tid == 0) scnt = 0;
  __syncthreads();

  for (int s = tid; s < S_TOK; s += 256) {
    if (expert_ws[s] == e) {
      const int p = atomicAdd(&scnt, 1);
      if (p < 1024) { su[p] = uval_ws[s]; sidx[p] = s; }  // n ~ 256±16; huge headroom
    }
  }
  __syncthreads();
  const int n = min(scnt, 1024);

  if (tid == 0) {
    counts_ws[e] = scnt;
    out[EC_OFF + e] = (float)scnt;   // exp_counts (pre-capacity)
  }

  for (int t = tid; t < n; t += 256) {
    int keep = 1;
    if (n > CAP) {
      const float ut = su[t];
      const int   it = sidx[t];
      int r = 0;
      for (int j = 0; j < n; ++j) {
        const float uj = su[j];
        r += (uj > ut) || (uj == ut && sidx[j] < it);
      }
      keep = (r < CAP);
    }
    skept[t] = keep;
  }
  __syncthreads();

  for (int t = tid; t < n; t += 256) {
    const int it = sidx[t];
    int sj = -1;
    if (skept[t]) {
      int slot = 0;
      for (int j = 0; j < n; ++j) slot += (skept[j] && (sidx[j] < it));
      sj = e * CAP + slot;
    }
    slotj_ws[it] = sj;
  }
}

// ---------------- K3: sparse scatter + l_aux (after memset in stream order) ----------------
__global__ __launch_bounds__(256) void k_scatter_final(
    const int* __restrict__ slotj_ws, const float* __restrict__ alpha_ws,
    const float* __restrict__ colsum_ws, const int* __restrict__ counts_ws,
    float* __restrict__ out)
{
  const int s = blockIdx.x * 256 + threadIdx.x;   // 64 blocks x 256 = 16384 tokens
  const int tj = slotj_ws[s];
  if (tj >= 0) {
    const size_t base = CW_OFF + (size_t)s * (NEXP * CAP) + (size_t)tj;
    out[base]       = alpha_ws[s];   // combine_weights
    out[base + SEC] = 1.0f;          // dispatch_mask
  }

  if (blockIdx.x == 0 && threadIdx.x < 64) {
    const int e = threadIdx.x;
    float cs = 0.f;
    for (int b = 0; b < GBLK; ++b) cs += colsum_ws[(size_t)b * 64 + e];  // fixed order
    const float me = cs / (float)S_TOK;
    const float ce = (float)counts_ws[e] / (float)S_TOK;
    float v = me * ce;
#pragma unroll
    for (int off = 32; off > 0; off >>= 1) v += __shfl_down(v, off, 64);
    if (e == 0) out[0] = v * (float)NEXP;
  }
}

// ---------------- launch ----------------
extern "C" void kernel_launch(void* const* d_in, const int* in_sizes, int n_in,
                              void* d_out, int out_size, void* d_ws, size_t ws_size,
                              hipStream_t stream)
{
  const float* x  = (const float*)d_in[0];
  const float* wg = (const float*)d_in[1];
  float* out = (float*)d_out;

  // workspace layout (~393 KB)
  char* ws = (char*)d_ws;
  int*   expert_ws = (int*)  (ws + 0);        // S ints
  float* uval_ws   = (float*)(ws + 65536);    // S floats
  float* alpha_ws  = (float*)(ws + 131072);   // S floats
  float* colsum_ws = (float*)(ws + 196608);   // GBLK*64 floats = 128 KB
  int*   counts_ws = (int*)  (ws + 327680);   // 64 ints
  int*   slotj_ws  = (int*)  (ws + 327936);   // S ints

  // Bulk zero via ROCclr fillBufferAligned (measured 6.36 TB/s on the poison fills).
  hipMemsetAsync(out, 0, (1 + 2 * SEC) * sizeof(float), stream);

  k_gate         <<<GBLK,        256, 0, stream>>>(x, wg, out, expert_ws, uval_ws,
                                                   alpha_ws, colsum_ws);
  k_select       <<<NEXP,        256, 0, stream>>>(expert_ws, uval_ws, slotj_ws,
                                                   counts_ws, out);
  k_scatter_final<<<S_TOK / 256, 256, 0, stream>>>(slotj_ws, alpha_ws, colsum_ws,
                                                   counts_ws, out);
}